// Round 3
// baseline (167.722 us; speedup 1.0000x reference)
//
#include <hip/hip_runtime.h>
#include <cfloat>

// Problem constants (from reference setup_inputs)
constexpr int B = 4;
constexpr int N = 8192;          // points per cloud (pred and gt both 8192)
constexpr int Q = 8;             // query points per thread
constexpr int BLK = 256;         // threads per block
constexpr int QPB = Q * BLK;     // 2048 queries per block
constexpr int NQG = N / QPB;     // 4 query groups per batch
constexpr int CHUNK = 256;       // target points staged per block
constexpr int NCH = N / CHUNK;   // 32 target chunks
constexpr int DIR_BLOCKS = B * NQG * NCH;   // 512
constexpr int MAIN_BLOCKS = 2 * DIR_BLOCKS; // 1024 (both directions, one launch)

// ws layout: uint mins[2][B][N] (min distances as float bit patterns),
// then uint counter (blocks-done).
constexpr int MINS_ELEMS = 2 * B * N;       // 65536
constexpr int NSEG = 2 * B;                 // 8 (dir,b) segments

__global__ __launch_bounds__(BLK) void chamfer_main(
        const float* __restrict__ pred, const float* __restrict__ gt,
        unsigned int* __restrict__ mins, unsigned int* __restrict__ counter,
        float* __restrict__ out) {
    int bid = blockIdx.x;
    int dir = bid / DIR_BLOCKS;       // 0: query=pred,target=gt ; 1: swapped
    int r   = bid % DIR_BLOCKS;
    int b   = r / (NQG * NCH);
    int r2  = r % (NQG * NCH);
    int qg  = r2 / NCH;
    int ch  = r2 % NCH;

    const float* qry = dir ? gt : pred;
    const float* tgt = dir ? pred : gt;
    unsigned int* omin = mins + dir * (B * N) + b * N;

    // Stage target chunk as (-2x, -2y, -2z, |g|^2): inner loop is then
    // t = dot3(p, g') + |g|^2 via 3 fma; d = t + |p|^2 folded out of loop.
    __shared__ float4 s[CHUNK];
    const float* tbase = tgt + (size_t)b * N * 3 + (size_t)ch * CHUNK * 3;
    if (threadIdx.x < CHUNK) {
        int j = threadIdx.x;
        float x = tbase[j * 3 + 0];
        float y = tbase[j * 3 + 1];
        float z = tbase[j * 3 + 2];
        s[j] = make_float4(-2.f * x, -2.f * y, -2.f * z,
                           fmaf(x, x, fmaf(y, y, z * z)));
    }
    __syncthreads();

    // Load Q query points per thread (stride BLK)
    float px[Q], py[Q], pz[Q], pn[Q], mn[Q];
    const float* qbase = qry + (size_t)b * N * 3 + (size_t)qg * QPB * 3;
#pragma unroll
    for (int q = 0; q < Q; ++q) {
        int qi = threadIdx.x + q * BLK;
        px[q] = qbase[qi * 3 + 0];
        py[q] = qbase[qi * 3 + 1];
        pz[q] = qbase[qi * 3 + 2];
        pn[q] = fmaf(px[q], px[q], fmaf(py[q], py[q], pz[q] * pz[q]));
        mn[q] = FLT_MAX;
    }

    // Inner loop: 2 targets per step; fminf(fminf(t0,t1), mn) -> v_min3_f32
    // => 3.5 VALU instr per pair. LDS reads are wave-wide broadcasts.
#pragma unroll 2
    for (int j = 0; j < CHUNK; j += 2) {
        float4 g0 = s[j];
        float4 g1 = s[j + 1];
#pragma unroll
        for (int q = 0; q < Q; ++q) {
            float t0 = fmaf(px[q], g0.x, fmaf(py[q], g0.y, fmaf(pz[q], g0.z, g0.w)));
            float t1 = fmaf(px[q], g1.x, fmaf(py[q], g1.y, fmaf(pz[q], g1.z, g1.w)));
            mn[q] = fminf(fminf(t0, t1), mn[q]);
        }
    }

#pragma unroll
    for (int q = 0; q < Q; ++q) {
        float d = fmaxf(mn[q] + pn[q], 0.f);   // clamp keeps uint-bit ordering valid
        int qi = qg * QPB + threadIdx.x + q * BLK;
        atomicMin(&omin[qi], __float_as_uint(d));   // device-scope by default
    }

    // ---- last-block-done tail reduction ----
    __shared__ unsigned int s_old;
    __threadfence();   // order atomicMins before the counter increment
    if (threadIdx.x == 0) {
        s_old = __hip_atomic_fetch_add(counter, 1u, __ATOMIC_ACQ_REL,
                                       __HIP_MEMORY_SCOPE_AGENT);
    }
    __syncthreads();
    if (s_old != (unsigned)(MAIN_BLOCKS - 1)) return;

    // This is the last block: all mins are final and visible (acq_rel + fences).
    // Read with agent-scope atomic loads (bypass potentially-stale caches).
    float sum = 0.f;
    float mx[NSEG];
#pragma unroll
    for (int a = 0; a < NSEG; ++a) {
        mx[a] = -FLT_MAX;
        const unsigned int* base = mins + (size_t)a * N;
        for (int i = threadIdx.x; i < N; i += BLK) {
            unsigned int u = __hip_atomic_load(base + i, __ATOMIC_RELAXED,
                                               __HIP_MEMORY_SCOPE_AGENT);
            float v = __uint_as_float(u);
            sum += v;
            mx[a] = fmaxf(mx[a], v);
        }
    }
    __shared__ float ssum[BLK];
    __shared__ float smax[NSEG][BLK];
    ssum[threadIdx.x] = sum;
#pragma unroll
    for (int a = 0; a < NSEG; ++a) smax[a][threadIdx.x] = mx[a];
    __syncthreads();
    for (int st = BLK / 2; st > 0; st >>= 1) {
        if (threadIdx.x < st) {
            ssum[threadIdx.x] += ssum[threadIdx.x + st];
#pragma unroll
            for (int a = 0; a < NSEG; ++a)
                smax[a][threadIdx.x] =
                    fmaxf(smax[a][threadIdx.x], smax[a][threadIdx.x + st]);
        }
        __syncthreads();
    }
    if (threadIdx.x == 0) {
        float hsum = 0.f;
#pragma unroll
        for (int a = 0; a < NSEG; ++a) hsum += smax[a][0];
        // chamfer = (sum of all mins)/(B*N); hausdorff = (sum of 8 maxes)/B
        out[0] = sum = ssum[0] / (float)(B * N);
        out[1] = hsum / (float)B;
    }
}

extern "C" void kernel_launch(void* const* d_in, const int* in_sizes, int n_in,
                              void* d_out, int out_size, void* d_ws, size_t ws_size,
                              hipStream_t stream) {
    const float* pred = (const float*)d_in[0];
    const float* gt   = (const float*)d_in[1];
    float* out = (float*)d_out;

    unsigned int* mins = (unsigned int*)d_ws;
    unsigned int* counter = mins + MINS_ELEMS;

    // 0xFFFFFFFF compares greater than any clamped non-negative float's bits.
    hipMemsetAsync(mins, 0xFF, (size_t)MINS_ELEMS * sizeof(unsigned int), stream);
    hipMemsetAsync(counter, 0, sizeof(unsigned int), stream);
    chamfer_main<<<MAIN_BLOCKS, BLK, 0, stream>>>(pred, gt, mins, counter, out);
}

// Round 4
// 56.065 us; speedup vs baseline: 2.9916x; 2.9916x over previous
//
#include <hip/hip_runtime.h>
#include <cfloat>

typedef float f32x2 __attribute__((ext_vector_type(2)));

// Packed dual FP32 FMA: d.lo = a.lo*b.lo + c.lo ; d.hi = a.hi*b.hi + c.hi
__device__ inline f32x2 pk_fma(f32x2 a, f32x2 b, f32x2 c) {
    f32x2 d;
    asm("v_pk_fma_f32 %0, %1, %2, %3" : "=v"(d) : "v"(a), "v"(b), "v"(c));
    return d;
}

// Problem constants (from reference setup_inputs)
constexpr int B = 4;
constexpr int N = 8192;          // points per cloud
constexpr int Q = 8;             // query points per thread
constexpr int BLK = 256;         // threads per block
constexpr int QPB = Q * BLK;     // 2048 queries per block
constexpr int NQG = N / QPB;     // 4 query groups per batch
constexpr int CHUNK = 512;       // target points staged per block
constexpr int PAIRS = CHUNK / 2; // 256 packed target pairs
constexpr int NCH = N / CHUNK;   // 16 target chunks
constexpr int DIR_BLOCKS = B * NQG * NCH;   // 256
constexpr int MAIN_BLOCKS = 2 * DIR_BLOCKS; // 512

constexpr int MINS_ELEMS = 2 * B * N;       // 65536
constexpr int NSEG = 2 * B;                 // 8 (dir,b) segments

__global__ __launch_bounds__(BLK) void chamfer_main(
        const float* __restrict__ pred, const float* __restrict__ gt,
        unsigned int* __restrict__ mins) {
    int bid = blockIdx.x;
    int dir = bid / DIR_BLOCKS;       // 0: query=pred,target=gt ; 1: swapped
    int r   = bid % DIR_BLOCKS;
    int b   = r / (NQG * NCH);
    int r2  = r % (NQG * NCH);
    int qg  = r2 / NCH;
    int ch  = r2 % NCH;

    const float* qry = dir ? gt : pred;
    const float* tgt = dir ? pred : gt;
    unsigned int* omin = mins + dir * (B * N) + b * N;

    // Stage target pairs packed for v_pk_fma_f32:
    //   sA[j2] = (-2x0, -2x1, -2y0, -2y1)
    //   sB[j2] = (-2z0, -2z1, |g0|^2, |g1|^2)
    // Inner loop: t(pair) = 3 pk_fma; d = t + |p|^2 folded out of loop.
    __shared__ float4 sA[PAIRS];
    __shared__ float4 sB[PAIRS];
    const float* tbase = tgt + (size_t)b * N * 3 + (size_t)ch * CHUNK * 3;
    {
        int j2 = threadIdx.x;  // one pair per thread (PAIRS == BLK)
        float x0 = tbase[j2 * 6 + 0], y0 = tbase[j2 * 6 + 1], z0 = tbase[j2 * 6 + 2];
        float x1 = tbase[j2 * 6 + 3], y1 = tbase[j2 * 6 + 4], z1 = tbase[j2 * 6 + 5];
        sA[j2] = make_float4(-2.f * x0, -2.f * x1, -2.f * y0, -2.f * y1);
        sB[j2] = make_float4(-2.f * z0, -2.f * z1,
                             fmaf(x0, x0, fmaf(y0, y0, z0 * z0)),
                             fmaf(x1, x1, fmaf(y1, y1, z1 * z1)));
    }
    __syncthreads();

    // Load Q query points per thread; duplicate coords into both packed halves.
    f32x2 qx[Q], qy[Q], qz[Q];
    float pn[Q], mn[Q];
    const float* qbase = qry + (size_t)b * N * 3 + (size_t)qg * QPB * 3;
#pragma unroll
    for (int q = 0; q < Q; ++q) {
        int qi = threadIdx.x + q * BLK;
        float px = qbase[qi * 3 + 0];
        float py = qbase[qi * 3 + 1];
        float pz = qbase[qi * 3 + 2];
        qx[q] = (f32x2){px, px};
        qy[q] = (f32x2){py, py};
        qz[q] = (f32x2){pz, pz};
        pn[q] = fmaf(px, px, fmaf(py, py, pz * pz));
        mn[q] = FLT_MAX;
    }

    // 2 targets per step: 3 pk_fma + 1 min3 per query => 2.0 instr/pair.
    // LDS reads are wave-wide broadcasts (conflict-free).
#pragma unroll 2
    for (int j2 = 0; j2 < PAIRS; ++j2) {
        float4 A  = sA[j2];
        float4 Bv = sB[j2];
        f32x2 xp = (f32x2){A.x,  A.y};
        f32x2 yp = (f32x2){A.z,  A.w};
        f32x2 zp = (f32x2){Bv.x, Bv.y};
        f32x2 wp = (f32x2){Bv.z, Bv.w};
#pragma unroll
        for (int q = 0; q < Q; ++q) {
            f32x2 t = pk_fma(qx[q], xp, pk_fma(qy[q], yp, pk_fma(qz[q], zp, wp)));
            mn[q] = fminf(fminf(t.x, t.y), mn[q]);   // -> v_min3_f32
        }
    }

#pragma unroll
    for (int q = 0; q < Q; ++q) {
        float d = fmaxf(mn[q] + pn[q], 0.f);   // clamp keeps uint-bit ordering valid
        int qi = qg * QPB + threadIdx.x + q * BLK;
        atomicMin(&omin[qi], __float_as_uint(d));
    }
}

// 8 blocks, one per (dir,b) segment; last block combines 16 partials.
__global__ __launch_bounds__(256) void reduce_seg(
        const unsigned int* __restrict__ mins, float* __restrict__ partials,
        unsigned int* __restrict__ counter, float* __restrict__ out) {
    int a = blockIdx.x;                 // 0..7
    const unsigned int* base = mins + (size_t)a * N;
    float sum = 0.f, mx = -FLT_MAX;
    for (int i = threadIdx.x; i < N / 4; i += 256) {
        uint4 u = ((const uint4*)base)[i];
        float v0 = __uint_as_float(u.x), v1 = __uint_as_float(u.y);
        float v2 = __uint_as_float(u.z), v3 = __uint_as_float(u.w);
        sum += (v0 + v1) + (v2 + v3);
        mx = fmaxf(fmaxf(fmaxf(mx, v0), fmaxf(v1, v2)), v3);
    }
    __shared__ float ssum[256], smax[256];
    ssum[threadIdx.x] = sum;
    smax[threadIdx.x] = mx;
    __syncthreads();
    for (int st = 128; st > 0; st >>= 1) {
        if (threadIdx.x < st) {
            ssum[threadIdx.x] += ssum[threadIdx.x + st];
            smax[threadIdx.x] = fmaxf(smax[threadIdx.x], smax[threadIdx.x + st]);
        }
        __syncthreads();
    }
    __shared__ unsigned int s_old;
    if (threadIdx.x == 0) {
        partials[a] = ssum[0];
        partials[NSEG + a] = smax[0];
        __threadfence();   // publish partials before counter bump
        s_old = __hip_atomic_fetch_add(counter, 1u, __ATOMIC_ACQ_REL,
                                       __HIP_MEMORY_SCOPE_AGENT);
        if (s_old == NSEG - 1) {
            float csum = 0.f, hsum = 0.f;
            for (int k = 0; k < NSEG; ++k) {
                csum += __uint_as_float(__hip_atomic_load(
                    (const unsigned int*)(partials + k),
                    __ATOMIC_RELAXED, __HIP_MEMORY_SCOPE_AGENT));
                hsum += __uint_as_float(__hip_atomic_load(
                    (const unsigned int*)(partials + NSEG + k),
                    __ATOMIC_RELAXED, __HIP_MEMORY_SCOPE_AGENT));
            }
            // chamfer = (sum of all mins)/(B*N); hausdorff = (sum of 8 maxes)/B
            out[0] = csum / (float)(B * N);
            out[1] = hsum / (float)B;
        }
    }
}

extern "C" void kernel_launch(void* const* d_in, const int* in_sizes, int n_in,
                              void* d_out, int out_size, void* d_ws, size_t ws_size,
                              hipStream_t stream) {
    const float* pred = (const float*)d_in[0];
    const float* gt   = (const float*)d_in[1];
    float* out = (float*)d_out;

    unsigned int* mins = (unsigned int*)d_ws;
    float* partials = (float*)(mins + MINS_ELEMS);
    unsigned int* counter = (unsigned int*)(partials + 2 * NSEG);

    // 0xFFFFFFFF compares greater than any clamped non-negative float's bits.
    hipMemsetAsync(mins, 0xFF, (size_t)MINS_ELEMS * sizeof(unsigned int), stream);
    hipMemsetAsync(counter, 0, sizeof(unsigned int), stream);
    chamfer_main<<<MAIN_BLOCKS, BLK, 0, stream>>>(pred, gt, mins);
    reduce_seg<<<NSEG, 256, 0, stream>>>(mins, partials, counter, out);
}

// Round 5
// 50.345 us; speedup vs baseline: 3.3314x; 1.1136x over previous
//
#include <hip/hip_runtime.h>
#include <cfloat>

typedef float f32x2 __attribute__((ext_vector_type(2)));

// Packed dual FP32 FMA (VOP3P). Half-rate per lane-pair but halves issue slots.
__device__ inline f32x2 pk_fma(f32x2 a, f32x2 b, f32x2 c) {
    f32x2 d;
    asm("v_pk_fma_f32 %0, %1, %2, %3" : "=v"(d) : "v"(a), "v"(b), "v"(c));
    return d;
}

// Problem constants (from reference setup_inputs)
constexpr int B = 4;
constexpr int N = 8192;          // points per cloud
constexpr int Q = 8;             // query points per thread
constexpr int BLK = 256;         // threads per block
constexpr int QPB = Q * BLK;     // 2048 queries per block
constexpr int NQG = N / QPB;     // 4 query groups per batch
constexpr int SQG = 2 * B * NQG; // 32 (dir,b,qg) query groups
constexpr int NSEG = 2 * B;      // 8 (dir,b) segments

// part[sqg][ch][QPB] partial mins; then bsum[256], bmax[256]
template <int NCH>
__global__ __launch_bounds__(BLK) void chamfer_main(
        const float* __restrict__ pred, const float* __restrict__ gt,
        float* __restrict__ part) {
    constexpr int CHUNK = N / NCH;
    constexpr int PAIRS = CHUNK / 2;
    int bid = blockIdx.x;
    int sqg = bid / NCH;              // (dir,b,qg) group
    int ch  = bid % NCH;
    int dir = sqg / (B * NQG);
    int rem = sqg % (B * NQG);
    int b   = rem / NQG;
    int qg  = rem % NQG;

    const float* qry = dir ? gt : pred;
    const float* tgt = dir ? pred : gt;

    // Stage target pairs packed for v_pk_fma_f32:
    //   sA[j2] = (-2x0, -2x1, -2y0, -2y1) ; sB[j2] = (-2z0, -2z1, n0, n1)
    __shared__ float4 sA[PAIRS];
    __shared__ float4 sB[PAIRS];
    const float* tbase = tgt + (size_t)b * N * 3 + (size_t)ch * CHUNK * 3;
    for (int j2 = threadIdx.x; j2 < PAIRS; j2 += BLK) {
        float x0 = tbase[j2 * 6 + 0], y0 = tbase[j2 * 6 + 1], z0 = tbase[j2 * 6 + 2];
        float x1 = tbase[j2 * 6 + 3], y1 = tbase[j2 * 6 + 4], z1 = tbase[j2 * 6 + 5];
        sA[j2] = make_float4(-2.f * x0, -2.f * x1, -2.f * y0, -2.f * y1);
        sB[j2] = make_float4(-2.f * z0, -2.f * z1,
                             fmaf(x0, x0, fmaf(y0, y0, z0 * z0)),
                             fmaf(x1, x1, fmaf(y1, y1, z1 * z1)));
    }
    __syncthreads();

    // Q query points per thread; coords duplicated into both packed halves.
    f32x2 qx[Q], qy[Q], qz[Q];
    float pn[Q], mn[Q];
    const float* qbase = qry + (size_t)b * N * 3 + (size_t)qg * QPB * 3;
#pragma unroll
    for (int q = 0; q < Q; ++q) {
        int qi = threadIdx.x + q * BLK;
        float px = qbase[qi * 3 + 0];
        float py = qbase[qi * 3 + 1];
        float pz = qbase[qi * 3 + 2];
        qx[q] = (f32x2){px, px};
        qy[q] = (f32x2){py, py};
        qz[q] = (f32x2){pz, pz};
        pn[q] = fmaf(px, px, fmaf(py, py, pz * pz));
        mn[q] = FLT_MAX;
    }

    // 2 targets/step: 3 pk_fma + 1 min3 per query. LDS reads broadcast.
#pragma unroll 2
    for (int j2 = 0; j2 < PAIRS; ++j2) {
        float4 A  = sA[j2];
        float4 Bv = sB[j2];
        f32x2 xp = (f32x2){A.x,  A.y};
        f32x2 yp = (f32x2){A.z,  A.w};
        f32x2 zp = (f32x2){Bv.x, Bv.y};
        f32x2 wp = (f32x2){Bv.z, Bv.w};
#pragma unroll
        for (int q = 0; q < Q; ++q) {
            f32x2 t = pk_fma(qx[q], xp, pk_fma(qy[q], yp, pk_fma(qz[q], zp, wp)));
            mn[q] = fminf(fminf(t.x, t.y), mn[q]);   // -> v_min3_f32
        }
    }

    // Plain coalesced stores to this block's unique slab — no atomics.
    float* po = part + ((size_t)sqg * NCH + ch) * QPB;
#pragma unroll
    for (int q = 0; q < Q; ++q)
        po[threadIdx.x + q * BLK] = fmaxf(mn[q] + pn[q], 0.f);
}

// 256 blocks; each handles 256 queries of one sqg group: min over NCH chunks,
// then block-level sum & max partials.
template <int NCH>
__global__ __launch_bounds__(256) void reduce1(
        const float* __restrict__ part, float* __restrict__ bsum,
        float* __restrict__ bmax) {
    constexpr int SUBS = QPB / 256;   // 8 blocks per sqg group
    int sqg = blockIdx.x / SUBS;
    int qi  = (blockIdx.x % SUBS) * 256 + threadIdx.x;
    const float* base = part + (size_t)sqg * NCH * QPB + qi;
    float v = FLT_MAX;
#pragma unroll
    for (int ch = 0; ch < NCH; ++ch)
        v = fminf(v, base[(size_t)ch * QPB]);   // coalesced across threads
    __shared__ float ssum[256], smax[256];
    ssum[threadIdx.x] = v;
    smax[threadIdx.x] = v;
    __syncthreads();
    for (int st = 128; st > 0; st >>= 1) {
        if (threadIdx.x < st) {
            ssum[threadIdx.x] += ssum[threadIdx.x + st];
            smax[threadIdx.x] = fmaxf(smax[threadIdx.x], smax[threadIdx.x + st]);
        }
        __syncthreads();
    }
    if (threadIdx.x == 0) {
        bsum[blockIdx.x] = ssum[0];
        bmax[blockIdx.x] = smax[0];
    }
}

// Combine 256 block partials. Blocks [seg*32, seg*32+32) belong to segment seg.
__global__ __launch_bounds__(256) void final_combine(
        const float* __restrict__ bsum, const float* __restrict__ bmax,
        float* __restrict__ out) {
    int t = threadIdx.x;
    __shared__ float ss[256], sm[256];
    ss[t] = bsum[t];
    sm[t] = bmax[t];
    __syncthreads();
    for (int st = 128; st > 0; st >>= 1) {
        if (t < st) ss[t] += ss[t + st];
        __syncthreads();
    }
    for (int st = 16; st > 0; st >>= 1) {
        if ((t & 31) < st) sm[t] = fmaxf(sm[t], sm[t + st]);
        __syncthreads();
    }
    if (t == 0) {
        float hsum = 0.f;
#pragma unroll
        for (int k = 0; k < NSEG; ++k) hsum += sm[k * 32];
        out[0] = ss[0] / (float)(B * N);   // chamfer
        out[1] = hsum / (float)B;          // hausdorff
    }
}

template <int NCH>
static void launch_all(const float* pred, const float* gt, void* d_ws,
                       float* out, hipStream_t stream) {
    float* part = (float*)d_ws;
    float* bsum = part + (size_t)SQG * NCH * QPB;
    float* bmax = bsum + 256;
    chamfer_main<NCH><<<SQG * NCH, BLK, 0, stream>>>(pred, gt, part);
    reduce1<NCH><<<256, 256, 0, stream>>>(part, bsum, bmax);
    final_combine<<<1, 256, 0, stream>>>(bsum, bmax, out);
}

extern "C" void kernel_launch(void* const* d_in, const int* in_sizes, int n_in,
                              void* d_out, int out_size, void* d_ws, size_t ws_size,
                              hipStream_t stream) {
    const float* pred = (const float*)d_in[0];
    const float* gt   = (const float*)d_in[1];
    float* out = (float*)d_out;

    auto need = [](int nch) {
        return (size_t)SQG * nch * QPB * sizeof(float) + 512 * sizeof(float);
    };
    if (ws_size >= need(32))      launch_all<32>(pred, gt, d_ws, out, stream);
    else if (ws_size >= need(16)) launch_all<16>(pred, gt, d_ws, out, stream);
    else if (ws_size >= need(8))  launch_all<8>(pred, gt, d_ws, out, stream);
    else                          launch_all<4>(pred, gt, d_ws, out, stream);
}